// Round 3
// baseline (1345.891 us; speedup 1.0000x reference)
//
#include <hip/hip_runtime.h>

// GraphConvolutionII: out = relu( (0.9 * segsum(val * x[col], row) + 0.1 * (x_init@w_init)) @ w_x )
// fp32 end-to-end. Primary: histogram -> scan -> bin (CSR) -> wave-per-row SpMM+blend
//                  -> in-place SGEMM+relu.
// Fallback (ws too small): blend-init + edge-parallel atomicAdd SpMM -> same SGEMM.

static constexpr int   NN = 100000;     // nodes
static constexpr int   NE = 3200000;    // edges
static constexpr float W_ALPHA = 0.9f;
static constexpr float W_OMA   = 0.1f;  // fp32(1.0 - 0.9 in python double) == 0.1f

// ---------------- histogram ----------------
__global__ void k_hist(const int* __restrict__ row, int* __restrict__ counts, int E) {
    int i = blockIdx.x * blockDim.x + threadIdx.x;
    int stride = gridDim.x * blockDim.x;
    for (; i < E; i += stride) atomicAdd(&counts[row[i]], 1);
}

// ---------------- exclusive scan (single block, 1024 thr) ----------------
__global__ void k_scan(const int* __restrict__ counts, int* __restrict__ off,
                       int* __restrict__ cursor, int N) {
    __shared__ int s_w[17];
    const int tid  = threadIdx.x;      // 0..1023
    const int lane = tid & 63;
    const int wid  = tid >> 6;         // 0..15
    int running = 0;
    for (int base = 0; base < N; base += 1024) {
        int i = base + tid;
        int v = (i < N) ? counts[i] : 0;
        int x = v;
        #pragma unroll
        for (int d = 1; d < 64; d <<= 1) {
            int t = __shfl_up(x, d);
            if (lane >= d) x += t;
        }
        if (lane == 63) s_w[wid] = x;
        __syncthreads();
        if (wid == 0) {
            int wv = (lane < 16) ? s_w[lane] : 0;
            int wx = wv;
            #pragma unroll
            for (int d = 1; d < 16; d <<= 1) {
                int t = __shfl_up(wx, d);
                if (lane >= d) wx += t;
            }
            if (lane < 16) s_w[lane] = wx - wv;   // exclusive wave offset
            if (lane == 15) s_w[16] = wx;         // chunk total
        }
        __syncthreads();
        int excl = running + s_w[wid] + (x - v);
        if (i < N) { off[i] = excl; cursor[i] = excl; }
        int tot = s_w[16];
        __syncthreads();                          // protect s_w before next chunk
        running += tot;
    }
    if (tid == 0) off[N] = running;
}

// ---------------- bin edges into CSR order ----------------
__global__ void k_scatter(const int* __restrict__ row, const int* __restrict__ col,
                          const float* __restrict__ val, int* __restrict__ cursor,
                          int* __restrict__ e_col, float* __restrict__ e_val, int E) {
    int i = blockIdx.x * blockDim.x + threadIdx.x;
    int stride = gridDim.x * blockDim.x;
    for (; i < E; i += stride) {
        int r = row[i];
        int p = atomicAdd(&cursor[r], 1);
        e_col[p] = col[i];
        e_val[p] = val[i];
    }
}

// ---------------- SpMM + alpha blend: one wave per node row ----------------
// Unroll-2 with dual accumulators: two independent 1KB gathers in flight per wave.
__global__ void k_spmm(const float* __restrict__ x, const float* __restrict__ xi,
                       const float* __restrict__ w_init,
                       const int* __restrict__ off, const int* __restrict__ e_col,
                       const float* __restrict__ e_val,
                       float* __restrict__ h /* == d_out */, int N) {
    const int lane = threadIdx.x & 63;
    const int wid  = threadIdx.x >> 6;
    const int r    = blockIdx.x * 4 + wid;
    if (r >= N) return;
    const int beg = off[r], end = off[r + 1];
    const float4* __restrict__ x4 = (const float4*)x;
    float4 acc0 = make_float4(0.f, 0.f, 0.f, 0.f);
    float4 acc1 = make_float4(0.f, 0.f, 0.f, 0.f);
    int k = beg;
    for (; k + 1 < end; k += 2) {
        int   c0 = e_col[k],     c1 = e_col[k + 1];
        float v0 = e_val[k],     v1 = e_val[k + 1];
        float4 a = x4[(size_t)c0 * 64 + lane];
        float4 b = x4[(size_t)c1 * 64 + lane];
        acc0.x += v0 * a.x; acc0.y += v0 * a.y; acc0.z += v0 * a.z; acc0.w += v0 * a.w;
        acc1.x += v1 * b.x; acc1.y += v1 * b.y; acc1.z += v1 * b.z; acc1.w += v1 * b.w;
    }
    if (k < end) {
        int   c = e_col[k];
        float v = e_val[k];
        float4 a = x4[(size_t)c * 64 + lane];
        acc0.x += v * a.x; acc0.y += v * a.y; acc0.z += v * a.z; acc0.w += v * a.w;
    }
    acc0.x += acc1.x; acc0.y += acc1.y; acc0.z += acc1.z; acc0.w += acc1.w;
    float i0 = xi[r * 3 + 0], i1 = xi[r * 3 + 1], i2 = xi[r * 3 + 2];
    const float4* __restrict__ w4 = (const float4*)w_init;
    float4 w0 = w4[lane], w1 = w4[64 + lane], w2 = w4[128 + lane];
    float4 hv;
    hv.x = W_ALPHA * acc0.x + W_OMA * (i0 * w0.x + i1 * w1.x + i2 * w2.x);
    hv.y = W_ALPHA * acc0.y + W_OMA * (i0 * w0.y + i1 * w1.y + i2 * w2.y);
    hv.z = W_ALPHA * acc0.z + W_OMA * (i0 * w0.z + i1 * w1.z + i2 * w2.z);
    hv.w = W_ALPHA * acc0.w + W_OMA * (i0 * w0.w + i1 * w1.w + i2 * w2.w);
    ((float4*)h)[(size_t)r * 64 + lane] = hv;
}

// ---------------- fallback: h = 0.1*(xi@w_init), one wave per row ----------------
__global__ void k_blend_init(const float* __restrict__ xi, const float* __restrict__ w_init,
                             float* __restrict__ h, int N) {
    const int lane = threadIdx.x & 63;
    const int wid  = threadIdx.x >> 6;
    const int r    = blockIdx.x * 4 + wid;
    if (r >= N) return;
    float i0 = xi[r * 3 + 0], i1 = xi[r * 3 + 1], i2 = xi[r * 3 + 2];
    const float4* __restrict__ w4 = (const float4*)w_init;
    float4 w0 = w4[lane], w1 = w4[64 + lane], w2 = w4[128 + lane];
    float4 hv;
    hv.x = W_OMA * (i0 * w0.x + i1 * w1.x + i2 * w2.x);
    hv.y = W_OMA * (i0 * w0.y + i1 * w1.y + i2 * w2.y);
    hv.z = W_OMA * (i0 * w0.z + i1 * w1.z + i2 * w2.z);
    hv.w = W_OMA * (i0 * w0.w + i1 * w1.w + i2 * w2.w);
    ((float4*)h)[(size_t)r * 64 + lane] = hv;
}

// ---------------- fallback: edge-parallel atomic scatter-add ----------------
__global__ void k_spmm_atomic(const float* __restrict__ x,
                              const int* __restrict__ row, const int* __restrict__ col,
                              const float* __restrict__ val,
                              float* __restrict__ h, int E) {
    const int lane = threadIdx.x & 63;
    const int wid  = threadIdx.x >> 6;
    int e = blockIdx.x * 4 + wid;
    const int estride = gridDim.x * 4;
    const float4* __restrict__ x4 = (const float4*)x;
    for (; e < E; e += estride) {
        int r = row[e], c = col[e];
        float v = W_ALPHA * val[e];
        float4 xv = x4[(size_t)c * 64 + lane];
        float* dst = h + (size_t)r * 256 + lane * 4;
        atomicAdd(dst + 0, v * xv.x);
        atomicAdd(dst + 1, v * xv.y);
        atomicAdd(dst + 2, v * xv.z);
        atomicAdd(dst + 3, v * xv.w);
    }
}

// ---------------- in-place SGEMM + relu: out = relu(h @ w_x) ----------------
// 64 rows x 256 cols per block (256 thr). Thread: 16 rows x 4 cols micro-tile.
// h-reads in the inner loop are wave-uniform (broadcast, conflict-free);
// only the w read is per-lane.
#define FMA4(A, S) { A.x += (S) * w.x; A.y += (S) * w.y; A.z += (S) * w.z; A.w += (S) * w.w; }
__global__ __launch_bounds__(256, 4)
void k_gemm_relu(float* __restrict__ hout, const float* __restrict__ wx, int M) {
    __shared__ float wsh[32][256];  // w_x[k][n] tile, 32 KB
    __shared__ float hsT[32][64];   // h[k][m] transposed, 8 KB
    const int tid  = threadIdx.x;
    const int rg   = tid >> 6;      // 0..3 row-group
    const int lane = tid & 63;      // col group: 4 cols at lane*4
    const int row0 = blockIdx.x * 64;

    float4 acc[16];
    #pragma unroll
    for (int i = 0; i < 16; ++i) acc[i] = make_float4(0.f, 0.f, 0.f, 0.f);

    for (int kk = 0; kk < 256; kk += 32) {
        {   // stage W tile 32x256
            int k  = tid >> 3;           // 0..31
            int c0 = (tid & 7) * 4;      // 0..28
            const float4* src = (const float4*)(wx + (size_t)(kk + k) * 256);
            #pragma unroll
            for (int c8 = 0; c8 < 8; ++c8) {
                float4 v = src[(c0 >> 2) + c8 * 8];
                *(float4*)&wsh[k][c0 + c8 * 32] = v;
            }
        }
        {   // stage H tile 64x32, transposed into hsT[k][m]
            int rr = tid >> 3;           // 0..31
            int k4 = (tid & 7) * 4;      // 0..28
            #pragma unroll
            for (int p = 0; p < 2; ++p) {
                int r = row0 + rr + p * 32;
                float4 v = make_float4(0.f, 0.f, 0.f, 0.f);
                if (r < M) v = *(const float4*)(hout + (size_t)r * 256 + kk + k4);
                hsT[k4 + 0][rr + p * 32] = v.x;
                hsT[k4 + 1][rr + p * 32] = v.y;
                hsT[k4 + 2][rr + p * 32] = v.z;
                hsT[k4 + 3][rr + p * 32] = v.w;
            }
        }
        __syncthreads();
        #pragma unroll
        for (int k = 0; k < 32; ++k) {
            float4 w  = *(const float4*)&wsh[k][lane * 4];
            float4 h0 = *(const float4*)&hsT[k][rg * 16 + 0];
            float4 h1 = *(const float4*)&hsT[k][rg * 16 + 4];
            float4 h2 = *(const float4*)&hsT[k][rg * 16 + 8];
            float4 h3 = *(const float4*)&hsT[k][rg * 16 + 12];
            FMA4(acc[0],  h0.x) FMA4(acc[1],  h0.y) FMA4(acc[2],  h0.z) FMA4(acc[3],  h0.w)
            FMA4(acc[4],  h1.x) FMA4(acc[5],  h1.y) FMA4(acc[6],  h1.z) FMA4(acc[7],  h1.w)
            FMA4(acc[8],  h2.x) FMA4(acc[9],  h2.y) FMA4(acc[10], h2.z) FMA4(acc[11], h2.w)
            FMA4(acc[12], h3.x) FMA4(acc[13], h3.y) FMA4(acc[14], h3.z) FMA4(acc[15], h3.w)
        }
        __syncthreads();
    }
    #pragma unroll
    for (int i = 0; i < 16; ++i) {
        int r = row0 + rg * 16 + i;
        if (r < M) {
            float4 v;
            v.x = fmaxf(acc[i].x, 0.f);
            v.y = fmaxf(acc[i].y, 0.f);
            v.z = fmaxf(acc[i].z, 0.f);
            v.w = fmaxf(acc[i].w, 0.f);
            *(float4*)(hout + (size_t)r * 256 + lane * 4) = v;
        }
    }
}

// ---------------- launch ----------------
static inline size_t alignup(size_t v, size_t a) { return (v + a - 1) & ~(a - 1); }

extern "C" void kernel_launch(void* const* d_in, const int* in_sizes, int n_in,
                              void* d_out, int out_size, void* d_ws, size_t ws_size,
                              hipStream_t stream) {
    const float* x       = (const float*)d_in[0];
    const float* x_init  = (const float*)d_in[1];
    const int*   adj_row = (const int*)d_in[2];
    const int*   adj_col = (const int*)d_in[3];
    const float* adj_val = (const float*)d_in[4];
    const float* w_init  = (const float*)d_in[5];
    const float* w_x     = (const float*)d_in[6];
    float* out = (float*)d_out;

    const size_t sz_counts = alignup((size_t)NN * 4, 256);
    const size_t sz_off    = alignup((size_t)(NN + 1) * 4, 256);
    const size_t sz_cursor = alignup((size_t)NN * 4, 256);
    const size_t sz_ecol   = alignup((size_t)NE * 4, 256);
    const size_t sz_eval   = alignup((size_t)NE * 4, 256);
    const size_t need = sz_counts + sz_off + sz_cursor + sz_ecol + sz_eval;

    if (ws_size >= need) {
        // ---- primary CSR path ----
        char* ws = (char*)d_ws;
        int*   counts = (int*)ws;    ws += sz_counts;
        int*   off    = (int*)ws;    ws += sz_off;
        int*   cursor = (int*)ws;    ws += sz_cursor;
        int*   e_col  = (int*)ws;    ws += sz_ecol;
        float* e_val  = (float*)ws;  ws += sz_eval;

        hipMemsetAsync(counts, 0, (size_t)NN * 4, stream);
        k_hist<<<2048, 256, 0, stream>>>(adj_row, counts, NE);
        k_scan<<<1, 1024, 0, stream>>>(counts, off, cursor, NN);
        k_scatter<<<2048, 256, 0, stream>>>(adj_row, adj_col, adj_val, cursor, e_col, e_val, NE);
        k_spmm<<<NN / 4, 256, 0, stream>>>(x, x_init, w_init, off, e_col, e_val, out, NN);
    } else {
        // ---- fallback: no scratch needed beyond d_out ----
        k_blend_init<<<NN / 4, 256, 0, stream>>>(x_init, w_init, out, NN);
        k_spmm_atomic<<<8192, 256, 0, stream>>>(x, adj_row, adj_col, adj_val, out, NE);
    }
    k_gemm_relu<<<(NN + 63) / 64, 256, 0, stream>>>(out, w_x, NN);
}

// Round 6
// 1205.585 us; speedup vs baseline: 1.1164x; 1.1164x over previous
//
#include <hip/hip_runtime.h>

// GraphConvolutionII: out = relu( (0.9*segsum(val*x[col], row) + 0.1*(x_init@w_init)) @ w_x )
// Reordered: y = 0.9*(x@w_x); wc = 0.1*(w_init@w_x); out = relu(A·y + x_init@wc)
// Pipeline: hist -> parallel scan(3) -> bin(CSR) -> GEMM(y) -> wc -> fused SpMM+bias+relu.
// Fallbacks: CSR-only (old order) if ws can't fit y; atomic path if ws tiny.

static constexpr int   NN = 100000;     // nodes
static constexpr int   NE = 3200000;    // edges
static constexpr float W_ALPHA = 0.9f;
static constexpr float W_OMA   = 0.1f;  // fp32(1.0 - 0.9 in python double) == 0.1f

typedef float f32x4 __attribute__((ext_vector_type(4)));  // nontemporal-builtin-compatible

// ---------------- histogram ----------------
__global__ void k_hist(const int* __restrict__ row, int* __restrict__ counts, int E) {
    int i = blockIdx.x * blockDim.x + threadIdx.x;
    int stride = gridDim.x * blockDim.x;
    for (; i < E; i += stride) atomicAdd(&counts[row[i]], 1);
}

// ---------------- parallel exclusive scan: 3 kernels ----------------
__global__ void k_scan_block(const int* __restrict__ counts, int* __restrict__ off,
                             int* __restrict__ btot, int N) {
    __shared__ int s_w[17];
    const int tid = threadIdx.x, lane = tid & 63, wid = tid >> 6;
    const int i = blockIdx.x * 1024 + tid;
    int v = (i < N) ? counts[i] : 0;
    int x = v;
    #pragma unroll
    for (int d = 1; d < 64; d <<= 1) {
        int t = __shfl_up(x, d);
        if (lane >= d) x += t;
    }
    if (lane == 63) s_w[wid] = x;
    __syncthreads();
    if (wid == 0) {
        int wv = (lane < 16) ? s_w[lane] : 0;
        int wx = wv;
        #pragma unroll
        for (int d = 1; d < 16; d <<= 1) {
            int t = __shfl_up(wx, d);
            if (lane >= d) wx += t;
        }
        if (lane < 16) s_w[lane] = wx - wv;   // exclusive wave offset
        if (lane == 15) s_w[16] = wx;         // block total
    }
    __syncthreads();
    if (i < N) off[i] = s_w[wid] + (x - v);
    if (tid == 0) btot[blockIdx.x] = s_w[16];
}

__global__ void k_scan_tops(const int* __restrict__ btot, int* __restrict__ boff,
                            int NB, int* __restrict__ total_out) {
    __shared__ int s[128];
    const int tid = threadIdx.x;
    int v = (tid < NB) ? btot[tid] : 0;
    s[tid] = v;
    __syncthreads();
    for (int d = 1; d < 128; d <<= 1) {
        int t = (tid >= d) ? s[tid - d] : 0;
        __syncthreads();
        s[tid] += t;
        __syncthreads();
    }
    if (tid < NB) boff[tid] = s[tid] - v;     // exclusive
    if (tid == NB - 1) *total_out = s[tid];
}

__global__ void k_scan_add(int* __restrict__ off, int* __restrict__ cursor,
                           const int* __restrict__ boff, int N) {
    const int i = blockIdx.x * 1024 + threadIdx.x;
    if (i < N) {
        int o = off[i] + boff[blockIdx.x];
        off[i] = o;
        cursor[i] = o;
    }
}

// ---------------- bin edges into CSR order ----------------
__global__ void k_scatter(const int* __restrict__ row, const int* __restrict__ col,
                          const float* __restrict__ val, int* __restrict__ cursor,
                          int* __restrict__ e_col, float* __restrict__ e_val, int E) {
    int i = blockIdx.x * blockDim.x + threadIdx.x;
    int stride = gridDim.x * blockDim.x;
    for (; i < E; i += stride) {
        int r = row[i];
        int p = atomicAdd(&cursor[r], 1);
        e_col[p] = col[i];
        e_val[p] = val[i];
    }
}

// ---------------- wc = 0.1 * (w_init @ w_x)  [3 x 256] ----------------
__global__ void k_wc(const float* __restrict__ wi, const float* __restrict__ wx,
                     float* __restrict__ wc) {
    const int n = threadIdx.x;  // 0..255
    float a0 = 0.f, a1 = 0.f, a2 = 0.f;
    for (int k = 0; k < 256; ++k) {
        float w = wx[k * 256 + n];
        a0 += wi[k] * w;
        a1 += wi[256 + k] * w;
        a2 += wi[512 + k] * w;
    }
    wc[n]       = W_OMA * a0;
    wc[256 + n] = W_OMA * a1;
    wc[512 + n] = W_OMA * a2;
}

// ---------------- fused SpMM + bias + relu: one wave per node row ----------------
// out[r] = relu( sum_e val*y[col] + x_init[r] @ wc ),  y already scaled by 0.9
// Unroll-4 with independent accumulators: 4 outstanding 1KB gathers per wave.
__global__ void k_spmm_fused(const float* __restrict__ y, const float* __restrict__ xi,
                             const float* __restrict__ wc,
                             const int* __restrict__ off, const int* __restrict__ e_col,
                             const float* __restrict__ e_val,
                             float* __restrict__ out, int N) {
    const int lane = threadIdx.x & 63;
    const int wid  = threadIdx.x >> 6;
    const int r    = blockIdx.x * 4 + wid;
    if (r >= N) return;
    const int beg = off[r], end = off[r + 1];
    const f32x4* __restrict__ y4 = (const f32x4*)y;
    f32x4 acc0 = {0.f, 0.f, 0.f, 0.f};
    f32x4 acc1 = {0.f, 0.f, 0.f, 0.f};
    f32x4 acc2 = {0.f, 0.f, 0.f, 0.f};
    f32x4 acc3 = {0.f, 0.f, 0.f, 0.f};
    int k = beg;
    for (; k + 3 < end; k += 4) {
        int   c0 = e_col[k],     c1 = e_col[k + 1];
        int   c2 = e_col[k + 2], c3 = e_col[k + 3];
        float v0 = e_val[k],     v1 = e_val[k + 1];
        float v2 = e_val[k + 2], v3 = e_val[k + 3];
        f32x4 a = y4[(size_t)c0 * 64 + lane];
        f32x4 b = y4[(size_t)c1 * 64 + lane];
        f32x4 c = y4[(size_t)c2 * 64 + lane];
        f32x4 d = y4[(size_t)c3 * 64 + lane];
        acc0 += v0 * a;
        acc1 += v1 * b;
        acc2 += v2 * c;
        acc3 += v3 * d;
    }
    for (; k < end; ++k) {
        int   c = e_col[k];
        float v = e_val[k];
        f32x4 a = y4[(size_t)c * 64 + lane];
        acc0 += v * a;
    }
    acc0 += acc1 + acc2 + acc3;
    float i0 = xi[r * 3 + 0], i1 = xi[r * 3 + 1], i2 = xi[r * 3 + 2];
    const f32x4* __restrict__ wc4 = (const f32x4*)wc;
    f32x4 b0 = wc4[lane], b1 = wc4[64 + lane], b2 = wc4[128 + lane];
    f32x4 hv = acc0 + i0 * b0 + i1 * b1 + i2 * b2;
    hv.x = fmaxf(hv.x, 0.f);
    hv.y = fmaxf(hv.y, 0.f);
    hv.z = fmaxf(hv.z, 0.f);
    hv.w = fmaxf(hv.w, 0.f);
    __builtin_nontemporal_store(hv, (f32x4*)out + (size_t)r * 64 + lane);  // out never re-read
}

// ---------------- GEMM: y = 0.9 * (x @ w_x), x streamed (nontemporal) ----------------
#define FMA4(A, S) { A.x += (S) * w.x; A.y += (S) * w.y; A.z += (S) * w.z; A.w += (S) * w.w; }
__global__ __launch_bounds__(256, 4)
void k_gemm_y(const float* __restrict__ xin, const float* __restrict__ wx,
              float* __restrict__ y, int M) {
    __shared__ float wsh[32][256];  // w_x[k][n] tile, 32 KB
    __shared__ float hsT[32][64];   // x[k][m] transposed, 8 KB
    const int tid  = threadIdx.x;
    const int rg   = tid >> 6;
    const int lane = tid & 63;
    const int row0 = blockIdx.x * 64;

    float4 acc[16];
    #pragma unroll
    for (int i = 0; i < 16; ++i) acc[i] = make_float4(0.f, 0.f, 0.f, 0.f);

    for (int kk = 0; kk < 256; kk += 32) {
        {   // stage W tile 32x256
            int k  = tid >> 3;
            int c0 = (tid & 7) * 4;
            const float4* src = (const float4*)(wx + (size_t)(kk + k) * 256);
            #pragma unroll
            for (int c8 = 0; c8 < 8; ++c8) {
                float4 v = src[(c0 >> 2) + c8 * 8];
                *(float4*)&wsh[k][c0 + c8 * 32] = v;
            }
        }
        {   // stage X tile 64x32 transposed (nontemporal: x read once)
            int rr = tid >> 3;
            int k4 = (tid & 7) * 4;
            #pragma unroll
            for (int p = 0; p < 2; ++p) {
                int r = row0 + rr + p * 32;
                f32x4 v = {0.f, 0.f, 0.f, 0.f};
                if (r < M) v = __builtin_nontemporal_load(
                    (const f32x4*)(xin + (size_t)r * 256 + kk + k4));
                hsT[k4 + 0][rr + p * 32] = v.x;
                hsT[k4 + 1][rr + p * 32] = v.y;
                hsT[k4 + 2][rr + p * 32] = v.z;
                hsT[k4 + 3][rr + p * 32] = v.w;
            }
        }
        __syncthreads();
        #pragma unroll
        for (int k = 0; k < 32; ++k) {
            float4 w  = *(const float4*)&wsh[k][lane * 4];
            float4 h0 = *(const float4*)&hsT[k][rg * 16 + 0];
            float4 h1 = *(const float4*)&hsT[k][rg * 16 + 4];
            float4 h2 = *(const float4*)&hsT[k][rg * 16 + 8];
            float4 h3 = *(const float4*)&hsT[k][rg * 16 + 12];
            FMA4(acc[0],  h0.x) FMA4(acc[1],  h0.y) FMA4(acc[2],  h0.z) FMA4(acc[3],  h0.w)
            FMA4(acc[4],  h1.x) FMA4(acc[5],  h1.y) FMA4(acc[6],  h1.z) FMA4(acc[7],  h1.w)
            FMA4(acc[8],  h2.x) FMA4(acc[9],  h2.y) FMA4(acc[10], h2.z) FMA4(acc[11], h2.w)
            FMA4(acc[12], h3.x) FMA4(acc[13], h3.y) FMA4(acc[14], h3.z) FMA4(acc[15], h3.w)
        }
        __syncthreads();
    }
    #pragma unroll
    for (int i = 0; i < 16; ++i) {
        int r = row0 + rg * 16 + i;
        if (r < M) {
            float4 v;
            v.x = W_ALPHA * acc[i].x;
            v.y = W_ALPHA * acc[i].y;
            v.z = W_ALPHA * acc[i].z;
            v.w = W_ALPHA * acc[i].w;
            *(float4*)(y + (size_t)r * 256 + lane * 4) = v;  // re-read by spmm: keep cached
        }
    }
}

// ---------------- fallback path kernels (round-3 validated) ----------------
__global__ void k_spmm(const float* __restrict__ x, const float* __restrict__ xi,
                       const float* __restrict__ w_init,
                       const int* __restrict__ off, const int* __restrict__ e_col,
                       const float* __restrict__ e_val,
                       float* __restrict__ h, int N) {
    const int lane = threadIdx.x & 63;
    const int wid  = threadIdx.x >> 6;
    const int r    = blockIdx.x * 4 + wid;
    if (r >= N) return;
    const int beg = off[r], end = off[r + 1];
    const float4* __restrict__ x4 = (const float4*)x;
    float4 acc0 = make_float4(0.f, 0.f, 0.f, 0.f);
    float4 acc1 = make_float4(0.f, 0.f, 0.f, 0.f);
    int k = beg;
    for (; k + 1 < end; k += 2) {
        int   c0 = e_col[k],     c1 = e_col[k + 1];
        float v0 = e_val[k],     v1 = e_val[k + 1];
        float4 a = x4[(size_t)c0 * 64 + lane];
        float4 b = x4[(size_t)c1 * 64 + lane];
        acc0.x += v0 * a.x; acc0.y += v0 * a.y; acc0.z += v0 * a.z; acc0.w += v0 * a.w;
        acc1.x += v1 * b.x; acc1.y += v1 * b.y; acc1.z += v1 * b.z; acc1.w += v1 * b.w;
    }
    if (k < end) {
        int   c = e_col[k];
        float v = e_val[k];
        float4 a = x4[(size_t)c * 64 + lane];
        acc0.x += v * a.x; acc0.y += v * a.y; acc0.z += v * a.z; acc0.w += v * a.w;
    }
    acc0.x += acc1.x; acc0.y += acc1.y; acc0.z += acc1.z; acc0.w += acc1.w;
    float i0 = xi[r * 3 + 0], i1 = xi[r * 3 + 1], i2 = xi[r * 3 + 2];
    const float4* __restrict__ w4 = (const float4*)w_init;
    float4 w0 = w4[lane], w1 = w4[64 + lane], w2 = w4[128 + lane];
    float4 hv;
    hv.x = W_ALPHA * acc0.x + W_OMA * (i0 * w0.x + i1 * w1.x + i2 * w2.x);
    hv.y = W_ALPHA * acc0.y + W_OMA * (i0 * w0.y + i1 * w1.y + i2 * w2.y);
    hv.z = W_ALPHA * acc0.z + W_OMA * (i0 * w0.z + i1 * w1.z + i2 * w2.z);
    hv.w = W_ALPHA * acc0.w + W_OMA * (i0 * w0.w + i1 * w1.w + i2 * w2.w);
    ((float4*)h)[(size_t)r * 64 + lane] = hv;
}

__global__ void k_blend_init(const float* __restrict__ xi, const float* __restrict__ w_init,
                             float* __restrict__ h, int N) {
    const int lane = threadIdx.x & 63;
    const int wid  = threadIdx.x >> 6;
    const int r    = blockIdx.x * 4 + wid;
    if (r >= N) return;
    float i0 = xi[r * 3 + 0], i1 = xi[r * 3 + 1], i2 = xi[r * 3 + 2];
    const float4* __restrict__ w4 = (const float4*)w_init;
    float4 w0 = w4[lane], w1 = w4[64 + lane], w2 = w4[128 + lane];
    float4 hv;
    hv.x = W_OMA * (i0 * w0.x + i1 * w1.x + i2 * w2.x);
    hv.y = W_OMA * (i0 * w0.y + i1 * w1.y + i2 * w2.y);
    hv.z = W_OMA * (i0 * w0.z + i1 * w1.z + i2 * w2.z);
    hv.w = W_OMA * (i0 * w0.w + i1 * w1.w + i2 * w2.w);
    ((float4*)h)[(size_t)r * 64 + lane] = hv;
}

__global__ void k_spmm_atomic(const float* __restrict__ x,
                              const int* __restrict__ row, const int* __restrict__ col,
                              const float* __restrict__ val,
                              float* __restrict__ h, int E) {
    const int lane = threadIdx.x & 63;
    const int wid  = threadIdx.x >> 6;
    int e = blockIdx.x * 4 + wid;
    const int estride = gridDim.x * 4;
    const float4* __restrict__ x4 = (const float4*)x;
    for (; e < E; e += estride) {
        int r = row[e], c = col[e];
        float v = W_ALPHA * val[e];
        float4 xv = x4[(size_t)c * 64 + lane];
        float* dst = h + (size_t)r * 256 + lane * 4;
        atomicAdd(dst + 0, v * xv.x);
        atomicAdd(dst + 1, v * xv.y);
        atomicAdd(dst + 2, v * xv.z);
        atomicAdd(dst + 3, v * xv.w);
    }
}

// in-place SGEMM + relu (fallback): out = relu(h @ w_x)
__global__ __launch_bounds__(256, 4)
void k_gemm_relu(float* __restrict__ hout, const float* __restrict__ wx, int M) {
    __shared__ float wsh[32][256];
    __shared__ float hsT[32][64];
    const int tid  = threadIdx.x;
    const int rg   = tid >> 6;
    const int lane = tid & 63;
    const int row0 = blockIdx.x * 64;

    float4 acc[16];
    #pragma unroll
    for (int i = 0; i < 16; ++i) acc[i] = make_float4(0.f, 0.f, 0.f, 0.f);

    for (int kk = 0; kk < 256; kk += 32) {
        {
            int k  = tid >> 3;
            int c0 = (tid & 7) * 4;
            const float4* src = (const float4*)(wx + (size_t)(kk + k) * 256);
            #pragma unroll
            for (int c8 = 0; c8 < 8; ++c8) {
                float4 v = src[(c0 >> 2) + c8 * 8];
                *(float4*)&wsh[k][c0 + c8 * 32] = v;
            }
        }
        {
            int rr = tid >> 3;
            int k4 = (tid & 7) * 4;
            #pragma unroll
            for (int p = 0; p < 2; ++p) {
                int r = row0 + rr + p * 32;
                float4 v = make_float4(0.f, 0.f, 0.f, 0.f);
                if (r < M) v = *(const float4*)(hout + (size_t)r * 256 + kk + k4);
                hsT[k4 + 0][rr + p * 32] = v.x;
                hsT[k4 + 1][rr + p * 32] = v.y;
                hsT[k4 + 2][rr + p * 32] = v.z;
                hsT[k4 + 3][rr + p * 32] = v.w;
            }
        }
        __syncthreads();
        #pragma unroll
        for (int k = 0; k < 32; ++k) {
            float4 w  = *(const float4*)&wsh[k][lane * 4];
            float4 h0 = *(const float4*)&hsT[k][rg * 16 + 0];
            float4 h1 = *(const float4*)&hsT[k][rg * 16 + 4];
            float4 h2 = *(const float4*)&hsT[k][rg * 16 + 8];
            float4 h3 = *(const float4*)&hsT[k][rg * 16 + 12];
            FMA4(acc[0],  h0.x) FMA4(acc[1],  h0.y) FMA4(acc[2],  h0.z) FMA4(acc[3],  h0.w)
            FMA4(acc[4],  h1.x) FMA4(acc[5],  h1.y) FMA4(acc[6],  h1.z) FMA4(acc[7],  h1.w)
            FMA4(acc[8],  h2.x) FMA4(acc[9],  h2.y) FMA4(acc[10], h2.z) FMA4(acc[11], h2.w)
            FMA4(acc[12], h3.x) FMA4(acc[13], h3.y) FMA4(acc[14], h3.z) FMA4(acc[15], h3.w)
        }
        __syncthreads();
    }
    #pragma unroll
    for (int i = 0; i < 16; ++i) {
        int r = row0 + rg * 16 + i;
        if (r < M) {
            float4 v;
            v.x = fmaxf(acc[i].x, 0.f);
            v.y = fmaxf(acc[i].y, 0.f);
            v.z = fmaxf(acc[i].z, 0.f);
            v.w = fmaxf(acc[i].w, 0.f);
            *(float4*)(hout + (size_t)r * 256 + lane * 4) = v;
        }
    }
}

// ---------------- launch ----------------
static inline size_t alignup(size_t v, size_t a) { return (v + a - 1) & ~(a - 1); }

extern "C" void kernel_launch(void* const* d_in, const int* in_sizes, int n_in,
                              void* d_out, int out_size, void* d_ws, size_t ws_size,
                              hipStream_t stream) {
    const float* x       = (const float*)d_in[0];
    const float* x_init  = (const float*)d_in[1];
    const int*   adj_row = (const int*)d_in[2];
    const int*   adj_col = (const int*)d_in[3];
    const float* adj_val = (const float*)d_in[4];
    const float* w_init  = (const float*)d_in[5];
    const float* w_x     = (const float*)d_in[6];
    float* out = (float*)d_out;

    const int NB = (NN + 1023) / 1024;  // scan blocks (98)

    const size_t sz_y      = alignup((size_t)NN * 256 * 4, 256);
    const size_t sz_counts = alignup((size_t)NN * 4, 256);
    const size_t sz_off    = alignup((size_t)(NN + 1) * 4, 256);
    const size_t sz_cursor = alignup((size_t)NN * 4, 256);
    const size_t sz_ecol   = alignup((size_t)NE * 4, 256);
    const size_t sz_eval   = alignup((size_t)NE * 4, 256);
    const size_t sz_btot   = alignup((size_t)NB * 4, 256);
    const size_t sz_wc     = alignup((size_t)3 * 256 * 4, 256);
    const size_t need_csr  = sz_counts + sz_off + sz_cursor + sz_ecol + sz_eval
                           + 2 * sz_btot;
    const size_t need_full = need_csr + sz_y + sz_wc;

    if (ws_size >= need_full) {
        // ---- primary: reordered fused path ----
        char* ws = (char*)d_ws;
        float* y      = (float*)ws;  ws += sz_y;
        float* wc     = (float*)ws;  ws += sz_wc;
        int*   counts = (int*)ws;    ws += sz_counts;
        int*   off    = (int*)ws;    ws += sz_off;
        int*   cursor = (int*)ws;    ws += sz_cursor;
        int*   btot   = (int*)ws;    ws += sz_btot;
        int*   boff   = (int*)ws;    ws += sz_btot;
        int*   e_col  = (int*)ws;    ws += sz_ecol;
        float* e_val  = (float*)ws;  ws += sz_eval;

        (void)hipMemsetAsync(counts, 0, (size_t)NN * 4, stream);
        k_hist<<<2048, 256, 0, stream>>>(adj_row, counts, NE);
        k_scan_block<<<NB, 1024, 0, stream>>>(counts, off, btot, NN);
        k_scan_tops<<<1, 128, 0, stream>>>(btot, boff, NB, off + NN);
        k_scan_add<<<NB, 1024, 0, stream>>>(off, cursor, boff, NN);
        k_scatter<<<2048, 256, 0, stream>>>(adj_row, adj_col, adj_val, cursor, e_col, e_val, NE);
        k_gemm_y<<<(NN + 63) / 64, 256, 0, stream>>>(x, w_x, y, NN);
        k_wc<<<1, 256, 0, stream>>>(w_init, w_x, wc);
        k_spmm_fused<<<NN / 4, 256, 0, stream>>>(y, x_init, wc, off, e_col, e_val, out, NN);
    } else if (ws_size >= need_csr) {
        // ---- CSR-only fallback (round-3 order, parallel scan) ----
        char* ws = (char*)d_ws;
        int*   counts = (int*)ws;    ws += sz_counts;
        int*   off    = (int*)ws;    ws += sz_off;
        int*   cursor = (int*)ws;    ws += sz_cursor;
        int*   btot   = (int*)ws;    ws += sz_btot;
        int*   boff   = (int*)ws;    ws += sz_btot;
        int*   e_col  = (int*)ws;    ws += sz_ecol;
        float* e_val  = (float*)ws;  ws += sz_eval;

        (void)hipMemsetAsync(counts, 0, (size_t)NN * 4, stream);
        k_hist<<<2048, 256, 0, stream>>>(adj_row, counts, NE);
        k_scan_block<<<NB, 1024, 0, stream>>>(counts, off, btot, NN);
        k_scan_tops<<<1, 128, 0, stream>>>(btot, boff, NB, off + NN);
        k_scan_add<<<NB, 1024, 0, stream>>>(off, cursor, boff, NN);
        k_scatter<<<2048, 256, 0, stream>>>(adj_row, adj_col, adj_val, cursor, e_col, e_val, NE);
        k_spmm<<<NN / 4, 256, 0, stream>>>(x, x_init, w_init, off, e_col, e_val, out, NN);
        k_gemm_relu<<<(NN + 63) / 64, 256, 0, stream>>>(out, w_x, NN);
    } else {
        // ---- minimal fallback ----
        k_blend_init<<<NN / 4, 256, 0, stream>>>(x_init, w_init, out, NN);
        k_spmm_atomic<<<8192, 256, 0, stream>>>(x, adj_row, adj_col, adj_val, out, NE);
        k_gemm_relu<<<(NN + 63) / 64, 256, 0, stream>>>(out, w_x, NN);
    }
}

// Round 7
// 985.322 us; speedup vs baseline: 1.3659x; 1.2235x over previous
//
#include <hip/hip_runtime.h>

// GraphConvolutionII: out = relu( (0.9*segsum(val*x[col], row) + 0.1*(x_init@w_init)) @ w_x )
// Reordered: y = bf16(0.9*(x@w_x)); wc = 0.1*(w_init@w_x); out = relu(A·y + x_init@wc)
// Pipeline: hist -> parallel scan(3) -> bin(CSR, packed int2) -> GEMM(y->bf16) -> wc
//           -> fused SpMM(bf16 gather, fp32 accum)+bias+relu.
// Fallbacks: fp32 CSR (round-3 validated) if ws can't fit y; atomic path if ws tiny.

static constexpr int   NN = 100000;     // nodes
static constexpr int   NE = 3200000;    // edges
static constexpr float W_ALPHA = 0.9f;
static constexpr float W_OMA   = 0.1f;  // fp32(1.0 - 0.9 in python double) == 0.1f

typedef float f32x4 __attribute__((ext_vector_type(4)));

// bf16 encode (round-to-nearest-even) / exact decode
__device__ __forceinline__ unsigned int bf16_rtn(float f) {
    unsigned int b = __float_as_uint(f);
    return (b + 0x7FFFu + ((b >> 16) & 1u)) >> 16;
}
__device__ __forceinline__ float bf16_dec(unsigned short u) {
    return __uint_as_float((unsigned int)u << 16);
}

// ---------------- histogram ----------------
__global__ void k_hist(const int* __restrict__ row, int* __restrict__ counts, int E) {
    int i = blockIdx.x * blockDim.x + threadIdx.x;
    int stride = gridDim.x * blockDim.x;
    for (; i < E; i += stride) atomicAdd(&counts[row[i]], 1);
}

// ---------------- parallel exclusive scan: 3 kernels ----------------
__global__ void k_scan_block(const int* __restrict__ counts, int* __restrict__ off,
                             int* __restrict__ btot, int N) {
    __shared__ int s_w[17];
    const int tid = threadIdx.x, lane = tid & 63, wid = tid >> 6;
    const int i = blockIdx.x * 1024 + tid;
    int v = (i < N) ? counts[i] : 0;
    int x = v;
    #pragma unroll
    for (int d = 1; d < 64; d <<= 1) {
        int t = __shfl_up(x, d);
        if (lane >= d) x += t;
    }
    if (lane == 63) s_w[wid] = x;
    __syncthreads();
    if (wid == 0) {
        int wv = (lane < 16) ? s_w[lane] : 0;
        int wx = wv;
        #pragma unroll
        for (int d = 1; d < 16; d <<= 1) {
            int t = __shfl_up(wx, d);
            if (lane >= d) wx += t;
        }
        if (lane < 16) s_w[lane] = wx - wv;   // exclusive wave offset
        if (lane == 15) s_w[16] = wx;         // block total
    }
    __syncthreads();
    if (i < N) off[i] = s_w[wid] + (x - v);
    if (tid == 0) btot[blockIdx.x] = s_w[16];
}

__global__ void k_scan_tops(const int* __restrict__ btot, int* __restrict__ boff,
                            int NB, int* __restrict__ total_out) {
    __shared__ int s[128];
    const int tid = threadIdx.x;
    int v = (tid < NB) ? btot[tid] : 0;
    s[tid] = v;
    __syncthreads();
    for (int d = 1; d < 128; d <<= 1) {
        int t = (tid >= d) ? s[tid - d] : 0;
        __syncthreads();
        s[tid] += t;
        __syncthreads();
    }
    if (tid < NB) boff[tid] = s[tid] - v;     // exclusive
    if (tid == NB - 1) *total_out = s[tid];
}

__global__ void k_scan_add(int* __restrict__ off, int* __restrict__ cursor,
                           const int* __restrict__ boff, int N) {
    const int i = blockIdx.x * 1024 + threadIdx.x;
    if (i < N) {
        int o = off[i] + boff[blockIdx.x];
        off[i] = o;
        cursor[i] = o;
    }
}

// ---------------- bin edges into CSR order (packed 8B) ----------------
__global__ void k_scatter_pack(const int* __restrict__ row, const int* __restrict__ col,
                               const float* __restrict__ val, int* __restrict__ cursor,
                               int2* __restrict__ e_pack, int E) {
    int i = blockIdx.x * blockDim.x + threadIdx.x;
    int stride = gridDim.x * blockDim.x;
    for (; i < E; i += stride) {
        int r = row[i];
        int p = atomicAdd(&cursor[r], 1);
        e_pack[p] = make_int2(col[i], __float_as_int(val[i]));  // one 8B line touch
    }
}

// ---------------- wc = 0.1 * (w_init @ w_x)  [3 x 256] ----------------
__global__ void k_wc(const float* __restrict__ wi, const float* __restrict__ wx,
                     float* __restrict__ wc) {
    const int n = threadIdx.x;  // 0..255
    float a0 = 0.f, a1 = 0.f, a2 = 0.f;
    for (int k = 0; k < 256; ++k) {
        float w = wx[k * 256 + n];
        a0 += wi[k] * w;
        a1 += wi[256 + k] * w;
        a2 += wi[512 + k] * w;
    }
    wc[n]       = W_OMA * a0;
    wc[256 + n] = W_OMA * a1;
    wc[512 + n] = W_OMA * a2;
}

// ---------------- fused SpMM (bf16 gather) + bias + relu ----------------
// out[r] = relu( sum_e val*y[col] + x_init[r] @ wc ),  y = bf16(0.9*x@w_x)
__global__ void k_spmm_fused(const unsigned short* __restrict__ y, const float* __restrict__ xi,
                             const float* __restrict__ wc,
                             const int* __restrict__ off, const int2* __restrict__ e_pack,
                             float* __restrict__ out, int N) {
    const int lane = threadIdx.x & 63;
    const int wid  = threadIdx.x >> 6;
    const int r    = blockIdx.x * 4 + wid;
    if (r >= N) return;
    const int beg = off[r], end = off[r + 1];
    const ushort4* __restrict__ y4 = (const ushort4*)y;   // 8B per lane per row
    f32x4 acc0 = {0.f, 0.f, 0.f, 0.f};
    f32x4 acc1 = {0.f, 0.f, 0.f, 0.f};
    f32x4 acc2 = {0.f, 0.f, 0.f, 0.f};
    f32x4 acc3 = {0.f, 0.f, 0.f, 0.f};
    int k = beg;
    for (; k + 3 < end; k += 4) {
        int2 e0 = e_pack[k],     e1 = e_pack[k + 1];
        int2 e2 = e_pack[k + 2], e3 = e_pack[k + 3];
        ushort4 a = y4[(size_t)e0.x * 64 + lane];
        ushort4 b = y4[(size_t)e1.x * 64 + lane];
        ushort4 c = y4[(size_t)e2.x * 64 + lane];
        ushort4 d = y4[(size_t)e3.x * 64 + lane];
        float v0 = __int_as_float(e0.y), v1 = __int_as_float(e1.y);
        float v2 = __int_as_float(e2.y), v3 = __int_as_float(e3.y);
        f32x4 fa = {bf16_dec(a.x), bf16_dec(a.y), bf16_dec(a.z), bf16_dec(a.w)};
        f32x4 fb = {bf16_dec(b.x), bf16_dec(b.y), bf16_dec(b.z), bf16_dec(b.w)};
        f32x4 fc = {bf16_dec(c.x), bf16_dec(c.y), bf16_dec(c.z), bf16_dec(c.w)};
        f32x4 fd = {bf16_dec(d.x), bf16_dec(d.y), bf16_dec(d.z), bf16_dec(d.w)};
        acc0 += v0 * fa;
        acc1 += v1 * fb;
        acc2 += v2 * fc;
        acc3 += v3 * fd;
    }
    for (; k < end; ++k) {
        int2 e = e_pack[k];
        ushort4 a = y4[(size_t)e.x * 64 + lane];
        float v = __int_as_float(e.y);
        f32x4 fa = {bf16_dec(a.x), bf16_dec(a.y), bf16_dec(a.z), bf16_dec(a.w)};
        acc0 += v * fa;
    }
    acc0 += acc1 + acc2 + acc3;
    float i0 = xi[r * 3 + 0], i1 = xi[r * 3 + 1], i2 = xi[r * 3 + 2];
    const f32x4* __restrict__ wc4 = (const f32x4*)wc;
    f32x4 b0 = wc4[lane], b1 = wc4[64 + lane], b2 = wc4[128 + lane];
    f32x4 hv = acc0 + i0 * b0 + i1 * b1 + i2 * b2;
    hv.x = fmaxf(hv.x, 0.f);
    hv.y = fmaxf(hv.y, 0.f);
    hv.z = fmaxf(hv.z, 0.f);
    hv.w = fmaxf(hv.w, 0.f);
    __builtin_nontemporal_store(hv, (f32x4*)out + (size_t)r * 64 + lane);  // out never re-read
}

// ---------------- GEMM: y = bf16(0.9 * (x @ w_x)), x streamed ----------------
#define FMA4(A, S) { A.x += (S) * w.x; A.y += (S) * w.y; A.z += (S) * w.z; A.w += (S) * w.w; }
__global__ __launch_bounds__(256, 4)
void k_gemm_y(const float* __restrict__ xin, const float* __restrict__ wx,
              unsigned short* __restrict__ y, int M) {
    __shared__ float wsh[32][256];  // w_x[k][n] tile, 32 KB
    __shared__ float hsT[32][64];   // x[k][m] transposed, 8 KB
    const int tid  = threadIdx.x;
    const int rg   = tid >> 6;
    const int lane = tid & 63;
    const int row0 = blockIdx.x * 64;

    float4 acc[16];
    #pragma unroll
    for (int i = 0; i < 16; ++i) acc[i] = make_float4(0.f, 0.f, 0.f, 0.f);

    for (int kk = 0; kk < 256; kk += 32) {
        {   // stage W tile 32x256
            int k  = tid >> 3;
            int c0 = (tid & 7) * 4;
            const float4* src = (const float4*)(wx + (size_t)(kk + k) * 256);
            #pragma unroll
            for (int c8 = 0; c8 < 8; ++c8) {
                float4 v = src[(c0 >> 2) + c8 * 8];
                *(float4*)&wsh[k][c0 + c8 * 32] = v;
            }
        }
        {   // stage X tile 64x32 transposed (nontemporal: x read once)
            int rr = tid >> 3;
            int k4 = (tid & 7) * 4;
            #pragma unroll
            for (int p = 0; p < 2; ++p) {
                int r = row0 + rr + p * 32;
                f32x4 v = {0.f, 0.f, 0.f, 0.f};
                if (r < M) v = __builtin_nontemporal_load(
                    (const f32x4*)(xin + (size_t)r * 256 + kk + k4));
                hsT[k4 + 0][rr + p * 32] = v.x;
                hsT[k4 + 1][rr + p * 32] = v.y;
                hsT[k4 + 2][rr + p * 32] = v.z;
                hsT[k4 + 3][rr + p * 32] = v.w;
            }
        }
        __syncthreads();
        #pragma unroll
        for (int k = 0; k < 32; ++k) {
            float4 w  = *(const float4*)&wsh[k][lane * 4];
            float4 h0 = *(const float4*)&hsT[k][rg * 16 + 0];
            float4 h1 = *(const float4*)&hsT[k][rg * 16 + 4];
            float4 h2 = *(const float4*)&hsT[k][rg * 16 + 8];
            float4 h3 = *(const float4*)&hsT[k][rg * 16 + 12];
            FMA4(acc[0],  h0.x) FMA4(acc[1],  h0.y) FMA4(acc[2],  h0.z) FMA4(acc[3],  h0.w)
            FMA4(acc[4],  h1.x) FMA4(acc[5],  h1.y) FMA4(acc[6],  h1.z) FMA4(acc[7],  h1.w)
            FMA4(acc[8],  h2.x) FMA4(acc[9],  h2.y) FMA4(acc[10], h2.z) FMA4(acc[11], h2.w)
            FMA4(acc[12], h3.x) FMA4(acc[13], h3.y) FMA4(acc[14], h3.z) FMA4(acc[15], h3.w)
        }
        __syncthreads();
    }
    #pragma unroll
    for (int i = 0; i < 16; ++i) {
        int r = row0 + rg * 16 + i;
        if (r < M) {
            // scale by 0.9 THEN round to bf16 (error scales with final magnitude)
            unsigned int u0 = bf16_rtn(W_ALPHA * acc[i].x);
            unsigned int u1 = bf16_rtn(W_ALPHA * acc[i].y);
            unsigned int u2 = bf16_rtn(W_ALPHA * acc[i].z);
            unsigned int u3 = bf16_rtn(W_ALPHA * acc[i].w);
            uint2 pk = make_uint2(u0 | (u1 << 16), u2 | (u3 << 16));
            *(uint2*)(y + (size_t)r * 256 + lane * 4) = pk;  // re-read by spmm: keep cached
        }
    }
}

// ---------------- fallback path kernels (round-3 validated, fp32 CSR) ----------------
__global__ void k_scatter(const int* __restrict__ row, const int* __restrict__ col,
                          const float* __restrict__ val, int* __restrict__ cursor,
                          int* __restrict__ e_col, float* __restrict__ e_val, int E) {
    int i = blockIdx.x * blockDim.x + threadIdx.x;
    int stride = gridDim.x * blockDim.x;
    for (; i < E; i += stride) {
        int r = row[i];
        int p = atomicAdd(&cursor[r], 1);
        e_col[p] = col[i];
        e_val[p] = val[i];
    }
}

__global__ void k_spmm(const float* __restrict__ x, const float* __restrict__ xi,
                       const float* __restrict__ w_init,
                       const int* __restrict__ off, const int* __restrict__ e_col,
                       const float* __restrict__ e_val,
                       float* __restrict__ h, int N) {
    const int lane = threadIdx.x & 63;
    const int wid  = threadIdx.x >> 6;
    const int r    = blockIdx.x * 4 + wid;
    if (r >= N) return;
    const int beg = off[r], end = off[r + 1];
    const float4* __restrict__ x4 = (const float4*)x;
    float4 acc0 = make_float4(0.f, 0.f, 0.f, 0.f);
    float4 acc1 = make_float4(0.f, 0.f, 0.f, 0.f);
    int k = beg;
    for (; k + 1 < end; k += 2) {
        int   c0 = e_col[k],     c1 = e_col[k + 1];
        float v0 = e_val[k],     v1 = e_val[k + 1];
        float4 a = x4[(size_t)c0 * 64 + lane];
        float4 b = x4[(size_t)c1 * 64 + lane];
        acc0.x += v0 * a.x; acc0.y += v0 * a.y; acc0.z += v0 * a.z; acc0.w += v0 * a.w;
        acc1.x += v1 * b.x; acc1.y += v1 * b.y; acc1.z += v1 * b.z; acc1.w += v1 * b.w;
    }
    if (k < end) {
        int   c = e_col[k];
        float v = e_val[k];
        float4 a = x4[(size_t)c * 64 + lane];
        acc0.x += v * a.x; acc0.y += v * a.y; acc0.z += v * a.z; acc0.w += v * a.w;
    }
    acc0.x += acc1.x; acc0.y += acc1.y; acc0.z += acc1.z; acc0.w += acc1.w;
    float i0 = xi[r * 3 + 0], i1 = xi[r * 3 + 1], i2 = xi[r * 3 + 2];
    const float4* __restrict__ w4 = (const float4*)w_init;
    float4 w0 = w4[lane], w1 = w4[64 + lane], w2 = w4[128 + lane];
    float4 hv;
    hv.x = W_ALPHA * acc0.x + W_OMA * (i0 * w0.x + i1 * w1.x + i2 * w2.x);
    hv.y = W_ALPHA * acc0.y + W_OMA * (i0 * w0.y + i1 * w1.y + i2 * w2.y);
    hv.z = W_ALPHA * acc0.z + W_OMA * (i0 * w0.z + i1 * w1.z + i2 * w2.z);
    hv.w = W_ALPHA * acc0.w + W_OMA * (i0 * w0.w + i1 * w1.w + i2 * w2.w);
    ((float4*)h)[(size_t)r * 64 + lane] = hv;
}

__global__ void k_blend_init(const float* __restrict__ xi, const float* __restrict__ w_init,
                             float* __restrict__ h, int N) {
    const int lane = threadIdx.x & 63;
    const int wid  = threadIdx.x >> 6;
    const int r    = blockIdx.x * 4 + wid;
    if (r >= N) return;
    float i0 = xi[r * 3 + 0], i1 = xi[r * 3 + 1], i2 = xi[r * 3 + 2];
    const float4* __restrict__ w4 = (const float4*)w_init;
    float4 w0 = w4[lane], w1 = w4[64 + lane], w2 = w4[128 + lane];
    float4 hv;
    hv.x = W_OMA * (i0 * w0.x + i1 * w1.x + i2 * w2.x);
    hv.y = W_OMA * (i0 * w0.y + i1 * w1.y + i2 * w2.y);
    hv.z = W_OMA * (i0 * w0.z + i1 * w1.z + i2 * w2.z);
    hv.w = W_OMA * (i0 * w0.w + i1 * w1.w + i2 * w2.w);
    ((float4*)h)[(size_t)r * 64 + lane] = hv;
}

__global__ void k_spmm_atomic(const float* __restrict__ x,
                              const int* __restrict__ row, const int* __restrict__ col,
                              const float* __restrict__ val,
                              float* __restrict__ h, int E) {
    const int lane = threadIdx.x & 63;
    const int wid  = threadIdx.x >> 6;
    int e = blockIdx.x * 4 + wid;
    const int estride = gridDim.x * 4;
    const float4* __restrict__ x4 = (const float4*)x;
    for (; e < E; e += estride) {
        int r = row[e], c = col[e];
        float v = W_ALPHA * val[e];
        float4 xv = x4[(size_t)c * 64 + lane];
        float* dst = h + (size_t)r * 256 + lane * 4;
        atomicAdd(dst + 0, v * xv.x);
        atomicAdd(dst + 1, v * xv.y);
        atomicAdd(dst + 2, v * xv.z);
        atomicAdd(dst + 3, v * xv.w);
    }
}

__global__ __launch_bounds__(256, 4)
void k_gemm_relu(float* __restrict__ hout, const float* __restrict__ wx, int M) {
    __shared__ float wsh[32][256];
    __shared__ float hsT[32][64];
    const int tid  = threadIdx.x;
    const int rg   = tid >> 6;
    const int lane = tid & 63;
    const int row0 = blockIdx.x * 64;

    float4 acc[16];
    #pragma unroll
    for (int i = 0; i < 16; ++i) acc[i] = make_float4(0.f, 0.f, 0.f, 0.f);

    for (int kk = 0; kk < 256; kk += 32) {
        {
            int k  = tid >> 3;
            int c0 = (tid & 7) * 4;
            const float4* src = (const float4*)(wx + (size_t)(kk + k) * 256);
            #pragma unroll
            for (int c8 = 0; c8 < 8; ++c8) {
                float4 v = src[(c0 >> 2) + c8 * 8];
                *(float4*)&wsh[k][c0 + c8 * 32] = v;
            }
        }
        {
            int rr = tid >> 3;
            int k4 = (tid & 7) * 4;
            #pragma unroll
            for (int p = 0; p < 2; ++p) {
                int r = row0 + rr + p * 32;
                float4 v = make_float4(0.f, 0.f, 0.f, 0.f);
                if (r < M) v = *(const float4*)(hout + (size_t)r * 256 + kk + k4);
                hsT[k4 + 0][rr + p * 32] = v.x;
                hsT[k4 + 1][rr + p * 32] = v.y;
                hsT[k4 + 2][rr + p * 32] = v.z;
                hsT[k4 + 3][rr + p * 32] = v.w;
            }
        }
        __syncthreads();
        #pragma unroll
        for (int k = 0; k < 32; ++k) {
            float4 w  = *(const float4*)&wsh[k][lane * 4];
            float4 h0 = *(const float4*)&hsT[k][rg * 16 + 0];
            float4 h1 = *(const float4*)&hsT[k][rg * 16 + 4];
            float4 h2 = *(const float4*)&hsT[k][rg * 16 + 8];
            float4 h3 = *(const float4*)&hsT[k][rg * 16 + 12];
            FMA4(acc[0],  h0.x) FMA4(acc[1],  h0.y) FMA4(acc[2],  h0.z) FMA4(acc[3],  h0.w)
            FMA4(acc[4],  h1.x) FMA4(acc[5],  h1.y) FMA4(acc[6],  h1.z) FMA4(acc[7],  h1.w)
            FMA4(acc[8],  h2.x) FMA4(acc[9],  h2.y) FMA4(acc[10], h2.z) FMA4(acc[11], h2.w)
            FMA4(acc[12], h3.x) FMA4(acc[13], h3.y) FMA4(acc[14], h3.z) FMA4(acc[15], h3.w)
        }
        __syncthreads();
    }
    #pragma unroll
    for (int i = 0; i < 16; ++i) {
        int r = row0 + rg * 16 + i;
        if (r < M) {
            float4 v;
            v.x = fmaxf(acc[i].x, 0.f);
            v.y = fmaxf(acc[i].y, 0.f);
            v.z = fmaxf(acc[i].z, 0.f);
            v.w = fmaxf(acc[i].w, 0.f);
            *(float4*)(hout + (size_t)r * 256 + lane * 4) = v;
        }
    }
}

// ---------------- launch ----------------
static inline size_t alignup(size_t v, size_t a) { return (v + a - 1) & ~(a - 1); }

extern "C" void kernel_launch(void* const* d_in, const int* in_sizes, int n_in,
                              void* d_out, int out_size, void* d_ws, size_t ws_size,
                              hipStream_t stream) {
    const float* x       = (const float*)d_in[0];
    const float* x_init  = (const float*)d_in[1];
    const int*   adj_row = (const int*)d_in[2];
    const int*   adj_col = (const int*)d_in[3];
    const float* adj_val = (const float*)d_in[4];
    const float* w_init  = (const float*)d_in[5];
    const float* w_x     = (const float*)d_in[6];
    float* out = (float*)d_out;

    const int NB = (NN + 1023) / 1024;  // scan blocks (98)

    const size_t sz_ybf    = alignup((size_t)NN * 256 * 2, 256);   // bf16 y, 51.2 MB
    const size_t sz_counts = alignup((size_t)NN * 4, 256);
    const size_t sz_off    = alignup((size_t)(NN + 1) * 4, 256);
    const size_t sz_cursor = alignup((size_t)NN * 4, 256);
    const size_t sz_epack  = alignup((size_t)NE * 8, 256);         // packed (col,val)
    const size_t sz_ecol   = alignup((size_t)NE * 4, 256);
    const size_t sz_eval   = alignup((size_t)NE * 4, 256);
    const size_t sz_btot   = alignup((size_t)NB * 4, 256);
    const size_t sz_wc     = alignup((size_t)3 * 256 * 4, 256);
    const size_t need_full = sz_counts + sz_off + sz_cursor + 2 * sz_btot
                           + sz_epack + sz_ybf + sz_wc;
    const size_t need_csr  = sz_counts + sz_off + sz_cursor + 2 * sz_btot
                           + sz_ecol + sz_eval;

    if (ws_size >= need_full) {
        // ---- primary: reordered fused path, bf16 y, packed edges ----
        char* ws = (char*)d_ws;
        unsigned short* y = (unsigned short*)ws;  ws += sz_ybf;
        float* wc     = (float*)ws;  ws += sz_wc;
        int*   counts = (int*)ws;    ws += sz_counts;
        int*   off    = (int*)ws;    ws += sz_off;
        int*   cursor = (int*)ws;    ws += sz_cursor;
        int*   btot   = (int*)ws;    ws += sz_btot;
        int*   boff   = (int*)ws;    ws += sz_btot;
        int2*  e_pack = (int2*)ws;   ws += sz_epack;

        (void)hipMemsetAsync(counts, 0, (size_t)NN * 4, stream);
        k_hist<<<2048, 256, 0, stream>>>(adj_row, counts, NE);
        k_scan_block<<<NB, 1024, 0, stream>>>(counts, off, btot, NN);
        k_scan_tops<<<1, 128, 0, stream>>>(btot, boff, NB, off + NN);
        k_scan_add<<<NB, 1024, 0, stream>>>(off, cursor, boff, NN);
        k_scatter_pack<<<2048, 256, 0, stream>>>(adj_row, adj_col, adj_val, cursor, e_pack, NE);
        k_gemm_y<<<(NN + 63) / 64, 256, 0, stream>>>(x, w_x, y, NN);
        k_wc<<<1, 256, 0, stream>>>(w_init, w_x, wc);
        k_spmm_fused<<<NN / 4, 256, 0, stream>>>(y, x_init, wc, off, e_pack, out, NN);
    } else if (ws_size >= need_csr) {
        // ---- CSR-only fallback (round-3 order, fp32, parallel scan) ----
        char* ws = (char*)d_ws;
        int*   counts = (int*)ws;    ws += sz_counts;
        int*   off    = (int*)ws;    ws += sz_off;
        int*   cursor = (int*)ws;    ws += sz_cursor;
        int*   btot   = (int*)ws;    ws += sz_btot;
        int*   boff   = (int*)ws;    ws += sz_btot;
        int*   e_col  = (int*)ws;    ws += sz_ecol;
        float* e_val  = (float*)ws;  ws += sz_eval;

        (void)hipMemsetAsync(counts, 0, (size_t)NN * 4, stream);
        k_hist<<<2048, 256, 0, stream>>>(adj_row, counts, NE);
        k_scan_block<<<NB, 1024, 0, stream>>>(counts, off, btot, NN);
        k_scan_tops<<<1, 128, 0, stream>>>(btot, boff, NB, off + NN);
        k_scan_add<<<NB, 1024, 0, stream>>>(off, cursor, boff, NN);
        k_scatter<<<2048, 256, 0, stream>>>(adj_row, adj_col, adj_val, cursor, e_col, e_val, NE);
        k_spmm<<<NN / 4, 256, 0, stream>>>(x, x_init, w_init, off, e_col, e_val, out, NN);
        k_gemm_relu<<<(NN + 63) / 64, 256, 0, stream>>>(out, w_x, NN);
    } else {
        // ---- minimal fallback ----
        k_blend_init<<<NN / 4, 256, 0, stream>>>(x_init, w_init, out, NN);
        k_spmm_atomic<<<8192, 256, 0, stream>>>(x, adj_row, adj_col, adj_val, out, NE);
        k_gemm_relu<<<(NN + 63) / 64, 256, 0, stream>>>(out, w_x, NN);
    }
}

// Round 9
// 901.729 us; speedup vs baseline: 1.4926x; 1.0927x over previous
//
#include <hip/hip_runtime.h>

// GraphConvolutionII: out = relu( (0.9*segsum(val*x[col], row) + 0.1*(x_init@w_init)) @ w_x )
// Reordered: y = bf16(0.9*(x@w_x)); wc = 0.1*(w_init@w_x); out = relu(A·y + x_init@wc)
// Pipeline: hist(XCD-part) -> parallel scan(3) -> bin(CSR, packed int2, XCD-part)
//           -> GEMM(y->bf16) -> wc -> fused SpMM(bf16 gather, fp32 accum)+bias+relu.
// XCD partitioning: destination rows split into 8 ranges; partition p runs on blocks
// with blockIdx%8==p (-> XCD p under round-robin dispatch), so each XCD's random
// writes stay within a 3.2MB slice that fits its 4MB L2 (kills the 8x write amp
// seen in round 7: WRITE_SIZE 199MB for a 25.6MB array). Streaming inputs use
// nontemporal loads so they don't evict the destination slice from L2.

static constexpr int   NN = 100000;     // nodes
static constexpr int   NE = 3200000;    // edges
static constexpr int   NPART = 8;       // XCD count; NN % NPART == 0 (12500 rows each)
static constexpr float W_ALPHA = 0.9f;
static constexpr float W_OMA   = 0.1f;  // fp32(1.0 - 0.9 in python double) == 0.1f

typedef float f32x4 __attribute__((ext_vector_type(4)));
typedef int   i32x2 __attribute__((ext_vector_type(2)));

// bf16 encode (round-to-nearest-even) / exact decode
__device__ __forceinline__ unsigned int bf16_rtn(float f) {
    unsigned int b = __float_as_uint(f);
    return (b + 0x7FFFu + ((b >> 16) & 1u)) >> 16;
}
__device__ __forceinline__ float bf16_dec(unsigned short u) {
    return __uint_as_float((unsigned int)u << 16);
}

// ---------------- histogram, XCD-partitioned ----------------
__global__ void k_hist_part(const int* __restrict__ row, int* __restrict__ counts, int E) {
    const int part = blockIdx.x & (NPART - 1);       // -> XCD id under round-robin
    const int rlo  = part * (NN / NPART);
    const int rhi  = rlo + (NN / NPART);
    int i = (blockIdx.x >> 3) * blockDim.x + threadIdx.x;
    const int stride = (gridDim.x >> 3) * blockDim.x;
    for (; i < E; i += stride) {
        int r = __builtin_nontemporal_load(row + i);   // stream: don't pollute L2
        if (r >= rlo && r < rhi) atomicAdd(&counts[r], 1);
    }
}

// plain histogram (fallback paths)
__global__ void k_hist(const int* __restrict__ row, int* __restrict__ counts, int E) {
    int i = blockIdx.x * blockDim.x + threadIdx.x;
    int stride = gridDim.x * blockDim.x;
    for (; i < E; i += stride) atomicAdd(&counts[row[i]], 1);
}

// ---------------- parallel exclusive scan: 3 kernels ----------------
__global__ void k_scan_block(const int* __restrict__ counts, int* __restrict__ off,
                             int* __restrict__ btot, int N) {
    __shared__ int s_w[17];
    const int tid = threadIdx.x, lane = tid & 63, wid = tid >> 6;
    const int i = blockIdx.x * 1024 + tid;
    int v = (i < N) ? counts[i] : 0;
    int x = v;
    #pragma unroll
    for (int d = 1; d < 64; d <<= 1) {
        int t = __shfl_up(x, d);
        if (lane >= d) x += t;
    }
    if (lane == 63) s_w[wid] = x;
    __syncthreads();
    if (wid == 0) {
        int wv = (lane < 16) ? s_w[lane] : 0;
        int wx = wv;
        #pragma unroll
        for (int d = 1; d < 16; d <<= 1) {
            int t = __shfl_up(wx, d);
            if (lane >= d) wx += t;
        }
        if (lane < 16) s_w[lane] = wx - wv;   // exclusive wave offset
        if (lane == 15) s_w[16] = wx;         // block total
    }
    __syncthreads();
    if (i < N) off[i] = s_w[wid] + (x - v);
    if (tid == 0) btot[blockIdx.x] = s_w[16];
}

__global__ void k_scan_tops(const int* __restrict__ btot, int* __restrict__ boff,
                            int NB, int* __restrict__ total_out) {
    __shared__ int s[128];
    const int tid = threadIdx.x;
    int v = (tid < NB) ? btot[tid] : 0;
    s[tid] = v;
    __syncthreads();
    for (int d = 1; d < 128; d <<= 1) {
        int t = (tid >= d) ? s[tid - d] : 0;
        __syncthreads();
        s[tid] += t;
        __syncthreads();
    }
    if (tid < NB) boff[tid] = s[tid] - v;     // exclusive
    if (tid == NB - 1) *total_out = s[tid];
}

__global__ void k_scan_add(int* __restrict__ off, int* __restrict__ cursor,
                           const int* __restrict__ boff, int N) {
    const int i = blockIdx.x * 1024 + threadIdx.x;
    if (i < N) {
        int o = off[i] + boff[blockIdx.x];
        off[i] = o;
        cursor[i] = o;
    }
}

// ---------------- bin edges into CSR order (packed 8B), XCD-partitioned ----------------
__global__ void k_scatter_part(const int* __restrict__ row, const int* __restrict__ col,
                               const float* __restrict__ val, int* __restrict__ cursor,
                               int2* __restrict__ e_pack, int E) {
    const int part = blockIdx.x & (NPART - 1);       // -> XCD id under round-robin
    const int rlo  = part * (NN / NPART);
    const int rhi  = rlo + (NN / NPART);
    int i = (blockIdx.x >> 3) * blockDim.x + threadIdx.x;
    const int stride = (gridDim.x >> 3) * blockDim.x;
    for (; i < E; i += stride) {
        int r = __builtin_nontemporal_load(row + i);   // stream
        if (r >= rlo && r < rhi) {
            int c = __builtin_nontemporal_load(col + i);
            float v = __builtin_nontemporal_load(val + i);
            int p = atomicAdd(&cursor[r], 1);
            e_pack[p] = make_int2(c, __float_as_int(v));  // 8B, slice-local (L2-held)
        }
    }
}

// plain scatter (fp32 CSR fallback)
__global__ void k_scatter(const int* __restrict__ row, const int* __restrict__ col,
                          const float* __restrict__ val, int* __restrict__ cursor,
                          int* __restrict__ e_col, float* __restrict__ e_val, int E) {
    int i = blockIdx.x * blockDim.x + threadIdx.x;
    int stride = gridDim.x * blockDim.x;
    for (; i < E; i += stride) {
        int r = row[i];
        int p = atomicAdd(&cursor[r], 1);
        e_col[p] = col[i];
        e_val[p] = val[i];
    }
}

// ---------------- wc = 0.1 * (w_init @ w_x)  [3 x 256] ----------------
__global__ void k_wc(const float* __restrict__ wi, const float* __restrict__ wx,
                     float* __restrict__ wc) {
    const int n = threadIdx.x;  // 0..255
    float a0 = 0.f, a1 = 0.f, a2 = 0.f;
    for (int k = 0; k < 256; ++k) {
        float w = wx[k * 256 + n];
        a0 += wi[k] * w;
        a1 += wi[256 + k] * w;
        a2 += wi[512 + k] * w;
    }
    wc[n]       = W_OMA * a0;
    wc[256 + n] = W_OMA * a1;
    wc[512 + n] = W_OMA * a2;
}

// ---------------- fused SpMM (bf16 gather) + bias + relu ----------------
__global__ void k_spmm_fused(const unsigned short* __restrict__ y, const float* __restrict__ xi,
                             const float* __restrict__ wc,
                             const int* __restrict__ off, const int2* __restrict__ e_pack,
                             float* __restrict__ out, int N) {
    const int lane = threadIdx.x & 63;
    const int wid  = threadIdx.x >> 6;
    const int r    = blockIdx.x * 4 + wid;
    if (r >= N) return;
    const int beg = off[r], end = off[r + 1];
    const ushort4* __restrict__ y4 = (const ushort4*)y;   // 8B per lane per row (cache these)
    const i32x2* __restrict__ ep = (const i32x2*)e_pack;  // stream these
    f32x4 acc0 = {0.f, 0.f, 0.f, 0.f};
    f32x4 acc1 = {0.f, 0.f, 0.f, 0.f};
    f32x4 acc2 = {0.f, 0.f, 0.f, 0.f};
    f32x4 acc3 = {0.f, 0.f, 0.f, 0.f};
    int k = beg;
    for (; k + 3 < end; k += 4) {
        i32x2 e0 = __builtin_nontemporal_load(ep + k);
        i32x2 e1 = __builtin_nontemporal_load(ep + k + 1);
        i32x2 e2 = __builtin_nontemporal_load(ep + k + 2);
        i32x2 e3 = __builtin_nontemporal_load(ep + k + 3);
        ushort4 a = y4[(size_t)e0.x * 64 + lane];
        ushort4 b = y4[(size_t)e1.x * 64 + lane];
        ushort4 c = y4[(size_t)e2.x * 64 + lane];
        ushort4 d = y4[(size_t)e3.x * 64 + lane];
        float v0 = __int_as_float(e0.y), v1 = __int_as_float(e1.y);
        float v2 = __int_as_float(e2.y), v3 = __int_as_float(e3.y);
        f32x4 fa = {bf16_dec(a.x), bf16_dec(a.y), bf16_dec(a.z), bf16_dec(a.w)};
        f32x4 fb = {bf16_dec(b.x), bf16_dec(b.y), bf16_dec(b.z), bf16_dec(b.w)};
        f32x4 fc = {bf16_dec(c.x), bf16_dec(c.y), bf16_dec(c.z), bf16_dec(c.w)};
        f32x4 fd = {bf16_dec(d.x), bf16_dec(d.y), bf16_dec(d.z), bf16_dec(d.w)};
        acc0 += v0 * fa;
        acc1 += v1 * fb;
        acc2 += v2 * fc;
        acc3 += v3 * fd;
    }
    for (; k < end; ++k) {
        i32x2 e = __builtin_nontemporal_load(ep + k);
        ushort4 a = y4[(size_t)e.x * 64 + lane];
        float v = __int_as_float(e.y);
        f32x4 fa = {bf16_dec(a.x), bf16_dec(a.y), bf16_dec(a.z), bf16_dec(a.w)};
        acc0 += v * fa;
    }
    acc0 += acc1 + acc2 + acc3;
    float i0 = xi[r * 3 + 0], i1 = xi[r * 3 + 1], i2 = xi[r * 3 + 2];
    const f32x4* __restrict__ wc4 = (const f32x4*)wc;
    f32x4 b0 = wc4[lane], b1 = wc4[64 + lane], b2 = wc4[128 + lane];
    f32x4 hv = acc0 + i0 * b0 + i1 * b1 + i2 * b2;
    hv.x = fmaxf(hv.x, 0.f);
    hv.y = fmaxf(hv.y, 0.f);
    hv.z = fmaxf(hv.z, 0.f);
    hv.w = fmaxf(hv.w, 0.f);
    __builtin_nontemporal_store(hv, (f32x4*)out + (size_t)r * 64 + lane);  // out never re-read
}

// ---------------- GEMM: y = bf16(0.9 * (x @ w_x)), x streamed ----------------
#define FMA4(A, S) { A.x += (S) * w.x; A.y += (S) * w.y; A.z += (S) * w.z; A.w += (S) * w.w; }
__global__ __launch_bounds__(256, 4)
void k_gemm_y(const float* __restrict__ xin, const float* __restrict__ wx,
              unsigned short* __restrict__ y, int M) {
    __shared__ float wsh[32][256];  // w_x[k][n] tile, 32 KB
    __shared__ float hsT[32][64];   // x[k][m] transposed, 8 KB
    const int tid  = threadIdx.x;
    const int rg   = tid >> 6;
    const int lane = tid & 63;
    const int row0 = blockIdx.x * 64;

    float4 acc[16];
    #pragma unroll
    for (int i = 0; i < 16; ++i) acc[i] = make_float4(0.f, 0.f, 0.f, 0.f);

    for (int kk = 0; kk < 256; kk += 32) {
        {   // stage W tile 32x256
            int k  = tid >> 3;
            int c0 = (tid & 7) * 4;
            const float4* src = (const float4*)(wx + (size_t)(kk + k) * 256);
            #pragma unroll
            for (int c8 = 0; c8 < 8; ++c8) {
                float4 v = src[(c0 >> 2) + c8 * 8];
                *(float4*)&wsh[k][c0 + c8 * 32] = v;
            }
        }
        {   // stage X tile 64x32 transposed (nontemporal: x read once)
            int rr = tid >> 3;
            int k4 = (tid & 7) * 4;
            #pragma unroll
            for (int p = 0; p < 2; ++p) {
                int r = row0 + rr + p * 32;
                f32x4 v = {0.f, 0.f, 0.f, 0.f};
                if (r < M) v = __builtin_nontemporal_load(
                    (const f32x4*)(xin + (size_t)r * 256 + kk + k4));
                hsT[k4 + 0][rr + p * 32] = v.x;
                hsT[k4 + 1][rr + p * 32] = v.y;
                hsT[k4 + 2][rr + p * 32] = v.z;
                hsT[k4 + 3][rr + p * 32] = v.w;
            }
        }
        __syncthreads();
        #pragma unroll
        for (int k = 0; k < 32; ++k) {
            float4 w  = *(const float4*)&wsh[k][lane * 4];
            float4 h0 = *(const float4*)&hsT[k][rg * 16 + 0];
            float4 h1 = *(const float4*)&hsT[k][rg * 16 + 4];
            float4 h2 = *(const float4*)&hsT[k][rg * 16 + 8];
            float4 h3 = *(const float4*)&hsT[k][rg * 16 + 12];
            FMA4(acc[0],  h0.x) FMA4(acc[1],  h0.y) FMA4(acc[2],  h0.z) FMA4(acc[3],  h0.w)
            FMA4(acc[4],  h1.x) FMA4(acc[5],  h1.y) FMA4(acc[6],  h1.z) FMA4(acc[7],  h1.w)
            FMA4(acc[8],  h2.x) FMA4(acc[9],  h2.y) FMA4(acc[10], h2.z) FMA4(acc[11], h2.w)
            FMA4(acc[12], h3.x) FMA4(acc[13], h3.y) FMA4(acc[14], h3.z) FMA4(acc[15], h3.w)
        }
        __syncthreads();
    }
    #pragma unroll
    for (int i = 0; i < 16; ++i) {
        int r = row0 + rg * 16 + i;
        if (r < M) {
            unsigned int u0 = bf16_rtn(W_ALPHA * acc[i].x);
            unsigned int u1 = bf16_rtn(W_ALPHA * acc[i].y);
            unsigned int u2 = bf16_rtn(W_ALPHA * acc[i].z);
            unsigned int u3 = bf16_rtn(W_ALPHA * acc[i].w);
            uint2 pk = make_uint2(u0 | (u1 << 16), u2 | (u3 << 16));
            *(uint2*)(y + (size_t)r * 256 + lane * 4) = pk;  // re-read by spmm: keep cached
        }
    }
}

// ---------------- fallback path kernels (round-3 validated, fp32 CSR) ----------------
__global__ void k_spmm(const float* __restrict__ x, const float* __restrict__ xi,
                       const float* __restrict__ w_init,
                       const int* __restrict__ off, const int* __restrict__ e_col,
                       const float* __restrict__ e_val,
                       float* __restrict__ h, int N) {
    const int lane = threadIdx.x & 63;
    const int wid  = threadIdx.x >> 6;
    const int r    = blockIdx.x * 4 + wid;
    if (r >= N) return;
    const int beg = off[r], end = off[r + 1];
    const float4* __restrict__ x4 = (const float4*)x;
    float4 acc0 = make_float4(0.f, 0.f, 0.f, 0.f);
    float4 acc1 = make_float4(0.f, 0.f, 0.f, 0.f);
    int k = beg;
    for (; k + 1 < end; k += 2) {
        int   c0 = e_col[k],     c1 = e_col[k + 1];
        float v0 = e_val[k],     v1 = e_val[k + 1];
        float4 a = x4[(size_t)c0 * 64 + lane];
        float4 b = x4[(size_t)c1 * 64 + lane];
        acc0.x += v0 * a.x; acc0.y += v0 * a.y; acc0.z += v0 * a.z; acc0.w += v0 * a.w;
        acc1.x += v1 * b.x; acc1.y += v1 * b.y; acc1.z += v1 * b.z; acc1.w += v1 * b.w;
    }
    if (k < end) {
        int   c = e_col[k];
        float v = e_val[k];
        float4 a = x4[(size_t)c * 64 + lane];
        acc0.x += v * a.x; acc0.y += v * a.y; acc0.z += v * a.z; acc0.w += v * a.w;
    }
    acc0.x += acc1.x; acc0.y += acc1.y; acc0.z += acc1.z; acc0.w += acc1.w;
    float i0 = xi[r * 3 + 0], i1 = xi[r * 3 + 1], i2 = xi[r * 3 + 2];
    const float4* __restrict__ w4 = (const float4*)w_init;
    float4 w0 = w4[lane], w1 = w4[64 + lane], w2 = w4[128 + lane];
    float4 hv;
    hv.x = W_ALPHA * acc0.x + W_OMA * (i0 * w0.x + i1 * w1.x + i2 * w2.x);
    hv.y = W_ALPHA * acc0.y + W_OMA * (i0 * w0.y + i1 * w1.y + i2 * w2.y);
    hv.z = W_ALPHA * acc0.z + W_OMA * (i0 * w0.z + i1 * w1.z + i2 * w2.z);
    hv.w = W_ALPHA * acc0.w + W_OMA * (i0 * w0.w + i1 * w1.w + i2 * w2.w);
    ((float4*)h)[(size_t)r * 64 + lane] = hv;
}

__global__ void k_blend_init(const float* __restrict__ xi, const float* __restrict__ w_init,
                             float* __restrict__ h, int N) {
    const int lane = threadIdx.x & 63;
    const int wid  = threadIdx.x >> 6;
    const int r    = blockIdx.x * 4 + wid;
    if (r >= N) return;
    float i0 = xi[r * 3 + 0], i1 = xi[r * 3 + 1], i2 = xi[r * 3 + 2];
    const float4* __restrict__ w4 = (const float4*)w_init;
    float4 w0 = w4[lane], w1 = w4[64 + lane], w2 = w4[128 + lane];
    float4 hv;
    hv.x = W_OMA * (i0 * w0.x + i1 * w1.x + i2 * w2.x);
    hv.y = W_OMA * (i0 * w0.y + i1 * w1.y + i2 * w2.y);
    hv.z = W_OMA * (i0 * w0.z + i1 * w1.z + i2 * w2.z);
    hv.w = W_OMA * (i0 * w0.w + i1 * w1.w + i2 * w2.w);
    ((float4*)h)[(size_t)r * 64 + lane] = hv;
}

__global__ void k_spmm_atomic(const float* __restrict__ x,
                              const int* __restrict__ row, const int* __restrict__ col,
                              const float* __restrict__ val,
                              float* __restrict__ h, int E) {
    const int lane = threadIdx.x & 63;
    const int wid  = threadIdx.x >> 6;
    int e = blockIdx.x * 4 + wid;
    const int estride = gridDim.x * 4;
    const float4* __restrict__ x4 = (const float4*)x;
    for (; e < E; e += estride) {
        int r = row[e], c = col[e];
        float v = W_ALPHA * val[e];
        float4 xv = x4[(size_t)c * 64 + lane];
        float* dst = h + (size_t)r * 256 + lane * 4;
        atomicAdd(dst + 0, v * xv.x);
        atomicAdd(dst + 1, v * xv.y);
        atomicAdd(dst + 2, v * xv.z);
        atomicAdd(dst + 3, v * xv.w);
    }
}

__global__ __launch_bounds__(256, 4)
void k_gemm_relu(float* __restrict__ hout, const float* __restrict__ wx, int M) {
    __shared__ float wsh[32][256];
    __shared__ float hsT[32][64];
    const int tid  = threadIdx.x;
    const int rg   = tid >> 6;
    const int lane = tid & 63;
    const int row0 = blockIdx.x * 64;

    float4 acc[16];
    #pragma unroll
    for (int i = 0; i < 16; ++i) acc[i] = make_float4(0.f, 0.f, 0.f, 0.f);

    for (int kk = 0; kk < 256; kk += 32) {
        {
            int k  = tid >> 3;
            int c0 = (tid & 7) * 4;
            const float4* src = (const float4*)(wx + (size_t)(kk + k) * 256);
            #pragma unroll
            for (int c8 = 0; c8 < 8; ++c8) {
                float4 v = src[(c0 >> 2) + c8 * 8];
                *(float4*)&wsh[k][c0 + c8 * 32] = v;
            }
        }
        {
            int rr = tid >> 3;
            int k4 = (tid & 7) * 4;
            #pragma unroll
            for (int p = 0; p < 2; ++p) {
                int r = row0 + rr + p * 32;
                float4 v = make_float4(0.f, 0.f, 0.f, 0.f);
                if (r < M) v = *(const float4*)(hout + (size_t)r * 256 + kk + k4);
                hsT[k4 + 0][rr + p * 32] = v.x;
                hsT[k4 + 1][rr + p * 32] = v.y;
                hsT[k4 + 2][rr + p * 32] = v.z;
                hsT[k4 + 3][rr + p * 32] = v.w;
            }
        }
        __syncthreads();
        #pragma unroll
        for (int k = 0; k < 32; ++k) {
            float4 w  = *(const float4*)&wsh[k][lane * 4];
            float4 h0 = *(const float4*)&hsT[k][rg * 16 + 0];
            float4 h1 = *(const float4*)&hsT[k][rg * 16 + 4];
            float4 h2 = *(const float4*)&hsT[k][rg * 16 + 8];
            float4 h3 = *(const float4*)&hsT[k][rg * 16 + 12];
            FMA4(acc[0],  h0.x) FMA4(acc[1],  h0.y) FMA4(acc[2],  h0.z) FMA4(acc[3],  h0.w)
            FMA4(acc[4],  h1.x) FMA4(acc[5],  h1.y) FMA4(acc[6],  h1.z) FMA4(acc[7],  h1.w)
            FMA4(acc[8],  h2.x) FMA4(acc[9],  h2.y) FMA4(acc[10], h2.z) FMA4(acc[11], h2.w)
            FMA4(acc[12], h3.x) FMA4(acc[13], h3.y) FMA4(acc[14], h3.z) FMA4(acc[15], h3.w)
        }
        __syncthreads();
    }
    #pragma unroll
    for (int i = 0; i < 16; ++i) {
        int r = row0 + rg * 16 + i;
        if (r < M) {
            float4 v;
            v.x = fmaxf(acc[i].x, 0.f);
            v.y = fmaxf(acc[i].y, 0.f);
            v.z = fmaxf(acc[i].z, 0.f);
            v.w = fmaxf(acc[i].w, 0.f);
            *(float4*)(hout + (size_t)r * 256 + lane * 4) = v;
        }
    }
}

// ---------------- launch ----------------
static inline size_t alignup(size_t v, size_t a) { return (v + a - 1) & ~(a - 1); }

extern "C" void kernel_launch(void* const* d_in, const int* in_sizes, int n_in,
                              void* d_out, int out_size, void* d_ws, size_t ws_size,
                              hipStream_t stream) {
    const float* x       = (const float*)d_in[0];
    const float* x_init  = (const float*)d_in[1];
    const int*   adj_row = (const int*)d_in[2];
    const int*   adj_col = (const int*)d_in[3];
    const float* adj_val = (const float*)d_in[4];
    const float* w_init  = (const float*)d_in[5];
    const float* w_x     = (const float*)d_in[6];
    float* out = (float*)d_out;

    const int NB = (NN + 1023) / 1024;  // scan blocks (98)

    const size_t sz_ybf    = alignup((size_t)NN * 256 * 2, 256);   // bf16 y, 51.2 MB
    const size_t sz_counts = alignup((size_t)NN * 4, 256);
    const size_t sz_off    = alignup((size_t)(NN + 1) * 4, 256);
    const size_t sz_cursor = alignup((size_t)NN * 4, 256);
    const size_t sz_epack  = alignup((size_t)NE * 8, 256);         // packed (col,val)
    const size_t sz_ecol   = alignup((size_t)NE * 4, 256);
    const size_t sz_eval   = alignup((size_t)NE * 4, 256);
    const size_t sz_btot   = alignup((size_t)NB * 4, 256);
    const size_t sz_wc     = alignup((size_t)3 * 256 * 4, 256);
    const size_t need_full = sz_counts + sz_off + sz_cursor + 2 * sz_btot
                           + sz_epack + sz_ybf + sz_wc;
    const size_t need_csr  = sz_counts + sz_off + sz_cursor + 2 * sz_btot
                           + sz_ecol + sz_eval;

    if (ws_size >= need_full) {
        // ---- primary: reordered fused path, bf16 y, packed edges, XCD-part binning ----
        char* ws = (char*)d_ws;
        unsigned short* y = (unsigned short*)ws;  ws += sz_ybf;
        float* wc     = (float*)ws;  ws += sz_wc;
        int*   counts = (int*)ws;    ws += sz_counts;
        int*   off    = (int*)ws;    ws += sz_off;
        int*   cursor = (int*)ws;    ws += sz_cursor;
        int*   btot   = (int*)ws;    ws += sz_btot;
        int*   boff   = (int*)ws;    ws += sz_btot;
        int2*  e_pack = (int2*)ws;   ws += sz_epack;

        (void)hipMemsetAsync(counts, 0, (size_t)NN * 4, stream);
        k_hist_part<<<2048, 256, 0, stream>>>(adj_row, counts, NE);
        k_scan_block<<<NB, 1024, 0, stream>>>(counts, off, btot, NN);
        k_scan_tops<<<1, 128, 0, stream>>>(btot, boff, NB, off + NN);
        k_scan_add<<<NB, 1024, 0, stream>>>(off, cursor, boff, NN);
        k_scatter_part<<<2048, 256, 0, stream>>>(adj_row, adj_col, adj_val, cursor, e_pack, NE);
        k_gemm_y<<<(NN + 63) / 64, 256, 0, stream>>>(x, w_x, y, NN);
        k_wc<<<1, 256, 0, stream>>>(w_init, w_x, wc);
        k_spmm_fused<<<NN / 4, 256, 0, stream>>>(y, x_init, wc, off, e_pack, out, NN);
    } else if (ws_size >= need_csr) {
        // ---- CSR-only fallback (round-3 order, fp32, parallel scan) ----
        char* ws = (char*)d_ws;
        int*   counts = (int*)ws;    ws += sz_counts;
        int*   off    = (int*)ws;    ws += sz_off;
        int*   cursor = (int*)ws;    ws += sz_cursor;
        int*   btot   = (int*)ws;    ws += sz_btot;
        int*   boff   = (int*)ws;    ws += sz_btot;
        int*   e_col  = (int*)ws;    ws += sz_ecol;
        float* e_val  = (float*)ws;  ws += sz_eval;

        (void)hipMemsetAsync(counts, 0, (size_t)NN * 4, stream);
        k_hist<<<2048, 256, 0, stream>>>(adj_row, counts, NE);
        k_scan_block<<<NB, 1024, 0, stream>>>(counts, off, btot, NN);
        k_scan_tops<<<1, 128, 0, stream>>>(btot, boff, NB, off + NN);
        k_scan_add<<<NB, 1024, 0, stream>>>(off, cursor, boff, NN);
        k_scatter<<<2048, 256, 0, stream>>>(adj_row, adj_col, adj_val, cursor, e_col, e_val, NE);
        k_spmm<<<NN / 4, 256, 0, stream>>>(x, x_init, w_init, off, e_col, e_val, out, NN);
        k_gemm_relu<<<(NN + 63) / 64, 256, 0, stream>>>(out, w_x, NN);
    } else {
        // ---- minimal fallback ----
        k_blend_init<<<NN / 4, 256, 0, stream>>>(x_init, w_init, out, NN);
        k_spmm_atomic<<<8192, 256, 0, stream>>>(x, adj_row, adj_col, adj_val, out, NE);
        k_gemm_relu<<<(NN + 63) / 64, 256, 0, stream>>>(out, w_x, NN);
    }
}